// Round 13
// baseline (504.966 us; speedup 1.0000x reference)
//
#include <hip/hip_runtime.h>
#include <hip/hip_cooperative_groups.h>

namespace cg = cooperative_groups;

#define N_NODES 20000
#define N_EDGES 160000
#define N_PAIRS 50000
#define DMAX 48
#define MB 64
#define NBLK 512
#define NTHR 256
#define NTOT (NBLK * NTHR)
// F_IN = CHANNELS = 32, EDGE_DIM = 8; G row = 288 floats (knw 256 + knb 32)

__device__ __forceinline__ float4 f4fma(float s, float4 w, float4 a) {
    a.x += s * w.x; a.y += s * w.y; a.z += s * w.z; a.w += s * w.w;
    return a;
}

// ---- gather phase: G[n][d*32+i] = sum e_d*X[src][i]; G[n][256+i] = sum X[src][i]
__device__ void gather_phase(const float* __restrict__ X, const float* __restrict__ E,
                             const int* __restrict__ cnt, const int2* __restrict__ adj,
                             float* __restrict__ G) {
    int gid = blockIdx.x * NTHR + threadIdx.x;
    int i = gid & 31;
    for (int n = gid >> 5; n < N_NODES; n += NTOT >> 5) {
        int deg = min(cnt[n], DMAX);
        float g0 = 0.f, g1 = 0.f, g2 = 0.f, g3 = 0.f;
        float g4 = 0.f, g5 = 0.f, g6 = 0.f, g7 = 0.f, g8 = 0.f;
        const int2* ap = adj + n * DMAX;
        if (deg > 0) {
            int2 se = ap[0];
            float4 ea = *(const float4*)(E + (size_t)se.y * 8);
            float4 eb = *(const float4*)(E + (size_t)se.y * 8 + 4);
            float xv = X[se.x * 32 + i];
            for (int k = 1; k < deg; ++k) {
                int2 se2 = ap[k];
                float4 ea2 = *(const float4*)(E + (size_t)se2.y * 8);
                float4 eb2 = *(const float4*)(E + (size_t)se2.y * 8 + 4);
                float xv2 = X[se2.x * 32 + i];
                g0 += ea.x * xv; g1 += ea.y * xv; g2 += ea.z * xv; g3 += ea.w * xv;
                g4 += eb.x * xv; g5 += eb.y * xv; g6 += eb.z * xv; g7 += eb.w * xv;
                g8 += xv;
                ea = ea2; eb = eb2; xv = xv2;
            }
            g0 += ea.x * xv; g1 += ea.y * xv; g2 += ea.z * xv; g3 += ea.w * xv;
            g4 += eb.x * xv; g5 += eb.y * xv; g6 += eb.z * xv; g7 += eb.w * xv;
            g8 += xv;
        }
        float* gr = G + (size_t)n * 288;
        gr[0 * 32 + i] = g0; gr[1 * 32 + i] = g1;
        gr[2 * 32 + i] = g2; gr[3 * 32 + i] = g3;
        gr[4 * 32 + i] = g4; gr[5 * 32 + i] = g5;
        gr[6 * 32 + i] = g6; gr[7 * 32 + i] = g7;
        gr[256 + i] = g8;
    }
}

// ---- epi phase: out[n][o] = sum_k Gext[n][k]*W'[k][o]; W' = [knw|knb|root]
// Gext rows 0..287 = G, 288..319 = X. Per chunk of 64 nodes.
__device__ void epi_phase(float* __restrict__ lds,
                          const float4* __restrict__ G4, const float4* __restrict__ X4,
                          const float4* __restrict__ knw4, const float4* __restrict__ knb4,
                          const float4* __restrict__ root4, const float* __restrict__ bias,
                          const float* __restrict__ dw, const float* __restrict__ db,
                          float* __restrict__ H, float* __restrict__ util, int mode) {
    float* Ws = lds;            // 320*32 = 10240 floats
    float* Gs = lds + 10240;    // 36*65  =  2340 floats
    int t = threadIdx.x;
    const int NCHUNK = (N_NODES + MB - 1) / MB;  // 313

    for (int cb = blockIdx.x; cb < NCHUNK; cb += NBLK) {
        int nb = cb * MB;
        // stage W' verbatim
        {
            float4* d = (float4*)Ws;
#pragma unroll
            for (int c = 0; c < 10; ++c) {
                int idx = c * 256 + t;
                float4 v;
                if (idx < 2048) v = knw4[idx];
                else if (idx < 2304) v = knb4[idx - 2048];
                else v = root4[idx - 2304];
                d[idx] = v;
            }
        }
        int mg = t >> 3, jg = t & 7;
        float4 a0 = make_float4(0.f, 0.f, 0.f, 0.f);
        float4 a1 = a0;
        int n0 = nb + 2 * mg, n1 = n0 + 1;

        for (int ch = 0; ch < 9; ++ch) {
            __syncthreads();
            if (ch < 8) {
                for (int idx = t; idx < MB * 9; idx += 256) {
                    int n = idx / 9, k4 = idx % 9;
                    float4 v = make_float4(0.f, 0.f, 0.f, 0.f);
                    if (nb + n < N_NODES) v = G4[(size_t)(nb + n) * 72 + ch * 9 + k4];
                    int r = k4 * 4;
                    Gs[(r + 0) * 65 + n] = v.x; Gs[(r + 1) * 65 + n] = v.y;
                    Gs[(r + 2) * 65 + n] = v.z; Gs[(r + 3) * 65 + n] = v.w;
                }
            } else {
                for (int idx = t; idx < MB * 8; idx += 256) {
                    int n = idx / 8, k4 = idx % 8;
                    float4 v = make_float4(0.f, 0.f, 0.f, 0.f);
                    if (nb + n < N_NODES) v = X4[(size_t)(nb + n) * 8 + k4];
                    int r = k4 * 4;
                    Gs[(r + 0) * 65 + n] = v.x; Gs[(r + 1) * 65 + n] = v.y;
                    Gs[(r + 2) * 65 + n] = v.z; Gs[(r + 3) * 65 + n] = v.w;
                }
            }
            __syncthreads();
            int kbase = (ch < 8) ? ch * 36 : 288;
            int klen = (ch < 8) ? 36 : 32;
            for (int kk = 0; kk < klen; ++kk) {
                float4 w = *(const float4*)&Ws[(kbase + kk) * 32 + jg * 4];
                float2 g = *(const float2*)&Gs[kk * 65 + 2 * mg];
                a0 = f4fma(g.x, w, a0);
                a1 = f4fma(g.y, w, a1);
            }
        }
        __syncthreads();  // Gs consumed before next chunk restages

        float4 b = ((const float4*)bias)[jg];
        if (mode == 0) {
            float4 v;
            if (n0 < N_NODES) {
                v.x = fmaxf(a0.x + b.x, 0.f); v.y = fmaxf(a0.y + b.y, 0.f);
                v.z = fmaxf(a0.z + b.z, 0.f); v.w = fmaxf(a0.w + b.w, 0.f);
                ((float4*)H)[n0 * 8 + jg] = v;
            }
            if (n1 < N_NODES) {
                v.x = fmaxf(a1.x + b.x, 0.f); v.y = fmaxf(a1.y + b.y, 0.f);
                v.z = fmaxf(a1.z + b.z, 0.f); v.w = fmaxf(a1.w + b.w, 0.f);
                ((float4*)H)[n1 * 8 + jg] = v;
            }
        } else {
            float4 dv = ((const float4*)dw)[jg];
            float p0 = fmaxf(a0.x + b.x, 0.f) * dv.x + fmaxf(a0.y + b.y, 0.f) * dv.y
                     + fmaxf(a0.z + b.z, 0.f) * dv.z + fmaxf(a0.w + b.w, 0.f) * dv.w;
            float p1 = fmaxf(a1.x + b.x, 0.f) * dv.x + fmaxf(a1.y + b.y, 0.f) * dv.y
                     + fmaxf(a1.z + b.z, 0.f) * dv.z + fmaxf(a1.w + b.w, 0.f) * dv.w;
            p0 += __shfl_xor(p0, 1); p1 += __shfl_xor(p1, 1);
            p0 += __shfl_xor(p0, 2); p1 += __shfl_xor(p1, 2);
            p0 += __shfl_xor(p0, 4); p1 += __shfl_xor(p1, 4);
            if (jg == 0) {
                float dbv = db[0];
                if (n0 < N_NODES) util[n0] = p0 + dbv;
                if (n1 < N_NODES) util[n1] = p1 + dbv;
            }
        }
    }
}

// ---- single cooperative kernel: all phases, 6 grid syncs ----
__global__ __launch_bounds__(NTHR) void fused_all(
        const float* __restrict__ x, const float* __restrict__ e,
        const float4* __restrict__ knw1, const float4* __restrict__ knb1,
        const float4* __restrict__ root1, const float* __restrict__ bias1,
        const float4* __restrict__ knw2, const float4* __restrict__ knb2,
        const float4* __restrict__ root2, const float* __restrict__ bias2,
        const float* __restrict__ dw, const float* __restrict__ db,
        const int* __restrict__ ei, const int* __restrict__ ia,
        const int* __restrict__ ib, float* __restrict__ out,
        float* __restrict__ G, float* __restrict__ H,
        float* __restrict__ util, int* __restrict__ cnt, int2* __restrict__ adj) {
    __shared__ float lds[12580];   // 50320 B: epi Ws+Gs
    cg::grid_group grid = cg::this_grid();
    int gid = blockIdx.x * NTHR + threadIdx.x;

    // P0: zero counters
    for (int idx = gid; idx < N_NODES; idx += NTOT) cnt[idx] = 0;
    grid.sync();

    // P1: adjacency fill
    for (int ee = gid; ee < N_EDGES; ee += NTOT) {
        int2 st = ((const int2*)ei)[ee];
        int slot = atomicAdd(&cnt[st.y], 1);
        if (slot < DMAX) adj[st.y * DMAX + slot] = make_int2(st.x, ee);
    }
    grid.sync();

    // P2: gather layer 1
    gather_phase(x, e, cnt, adj, G);
    grid.sync();

    // P3: epi layer 1 -> H
    epi_phase(lds, (const float4*)G, (const float4*)x, knw1, knb1, root1,
              bias1, dw, db, H, util, 0);
    grid.sync();

    // P4: gather layer 2
    gather_phase(H, e, cnt, adj, G);
    grid.sync();

    // P5: epi layer 2 -> util
    epi_phase(lds, (const float4*)G, (const float4*)H, knw2, knb2, root2,
              bias2, dw, db, H, util, 1);
    grid.sync();

    // P6: pairs
    for (int p = gid; p < N_PAIRS; p += NTOT) out[p] = util[ib[p]] - util[ia[p]];
}

extern "C" void kernel_launch(void* const* d_in, const int* in_sizes, int n_in,
                              void* d_out, int out_size, void* d_ws, size_t ws_size,
                              hipStream_t stream) {
    const float* x     = (const float*)d_in[0];
    const float* e     = (const float*)d_in[1];
    const float4* knw1 = (const float4*)d_in[2];
    const float4* knb1 = (const float4*)d_in[3];
    const float4* root1= (const float4*)d_in[4];
    const float* bias1 = (const float*)d_in[5];
    const float4* knw2 = (const float4*)d_in[6];
    const float4* knb2 = (const float4*)d_in[7];
    const float4* root2= (const float4*)d_in[8];
    const float* bias2 = (const float*)d_in[9];
    const float* dw    = (const float*)d_in[10];
    const float* db    = (const float*)d_in[11];
    const int*   ei    = (const int*)d_in[12];
    const int*   ia    = (const int*)d_in[13];
    const int*   ib    = (const int*)d_in[14];
    float* out = (float*)d_out;

    float* ws = (float*)d_ws;
    float* G    = ws;                       // 20000*288 = 5,760,000 floats
    float* H    = ws + 5760000;             // 640,000
    float* util = ws + 6400000;             // 20,000
    int*   cnt  = (int*)(ws + 6420000);     // 20,000
    int2*  adj  = (int2*)(ws + 6440000);    // 960,000 int2 (8B aligned)

    void* args[] = {
        (void*)&x, (void*)&e,
        (void*)&knw1, (void*)&knb1, (void*)&root1, (void*)&bias1,
        (void*)&knw2, (void*)&knb2, (void*)&root2, (void*)&bias2,
        (void*)&dw, (void*)&db,
        (void*)&ei, (void*)&ia, (void*)&ib, (void*)&out,
        (void*)&G, (void*)&H, (void*)&util, (void*)&cnt, (void*)&adj,
    };
    hipLaunchCooperativeKernel((void*)fused_all, dim3(NBLK), dim3(NTHR),
                               args, 0, stream);
}

// Round 15
// 104.009 us; speedup vs baseline: 4.8550x; 4.8550x over previous
//
#include <hip/hip_runtime.h>

#define N_NODES 20000
#define N_EDGES 160000
#define N_PAIRS 50000
#define DMAX 48
#define MB 64          // nodes per epi block
// F_IN = CHANNELS = 32, EDGE_DIM = 8; G row = 288 floats (knw 256 + knb 32)

__device__ __forceinline__ float4 f4fma(float s, float4 w, float4 a) {
    a.x += s * w.x; a.y += s * w.y; a.z += s * w.z; a.w += s * w.w;
    return a;
}

__global__ void zero_cnt(int* __restrict__ c) {
    int t = blockIdx.x * blockDim.x + threadIdx.x;
    if (t < N_NODES) c[t] = 0;
}

// adjacency by target: slot -> int2(src node, edge id). 8 B/slot.
__global__ __launch_bounds__(256) void fill_adj(const int* __restrict__ ei,
                                                int* __restrict__ cnt,
                                                int2* __restrict__ adj) {
    int e = blockIdx.x * blockDim.x + threadIdx.x;
    if (e >= N_EDGES) return;
    int2 st = ((const int2*)ei)[e];  // x = src, y = tgt
    int slot = atomicAdd(&cnt[st.y], 1);
    if (slot < DMAX) adj[st.y * DMAX + slot] = make_int2(st.x, e);
}

#define EDGE_FMA(ea, eb, xv)                                                   \
    g0 += (ea).x * (xv); g1 += (ea).y * (xv); g2 += (ea).z * (xv);             \
    g3 += (ea).w * (xv); g4 += (eb).x * (xv); g5 += (eb).y * (xv);             \
    g6 += (eb).z * (xv); g7 += (eb).w * (xv); g8 += (xv);

// G gather: ONE WAVE PER NODE. lane = (half, i): i = channel, half = edge split.
// Edges in chunks of 8 (4 per half): 4 adj slots loaded as 4 independent int2
// loads (NO int4 aliasing of the int2-written table), then all 8 E-float4s +
// 4 X-floats issued before any FMA -> ~1 exposed latency round per chunk.
//   G[n][d*32+i] = sum_{e->n} e_d * X[src][i];  G[n][256+i] = sum X[src][i]
__global__ __launch_bounds__(256) void edge_gather(const float* __restrict__ X,
                                                   const float* __restrict__ E,
                                                   const int* __restrict__ cnt,
                                                   const int2* __restrict__ adj,
                                                   float* __restrict__ G) {
    int t = blockIdx.x * blockDim.x + threadIdx.x;
    int n = t >> 6;
    if (n >= N_NODES) return;
    int lane = t & 63;
    int i = lane & 31;
    int half = lane >> 5;

    int deg = min(cnt[n], DMAX);
    int base = n * DMAX;
    float g0 = 0.f, g1 = 0.f, g2 = 0.f, g3 = 0.f;
    float g4 = 0.f, g5 = 0.f, g6 = 0.f, g7 = 0.f, g8 = 0.f;

    // full chunks of 8 edges (4 per half)
    int c = 0;
    for (; c + 8 <= deg; c += 8) {
        const int2* ap = adj + base + c + half * 4;
        int2 s0 = ap[0];
        int2 s1 = ap[1];
        int2 s2 = ap[2];
        int2 s3 = ap[3];
        float4 ea0 = *(const float4*)(E + (size_t)s0.y * 8);
        float4 eb0 = *(const float4*)(E + (size_t)s0.y * 8 + 4);
        float4 ea1 = *(const float4*)(E + (size_t)s1.y * 8);
        float4 eb1 = *(const float4*)(E + (size_t)s1.y * 8 + 4);
        float4 ea2 = *(const float4*)(E + (size_t)s2.y * 8);
        float4 eb2 = *(const float4*)(E + (size_t)s2.y * 8 + 4);
        float4 ea3 = *(const float4*)(E + (size_t)s3.y * 8);
        float4 eb3 = *(const float4*)(E + (size_t)s3.y * 8 + 4);
        float xv0 = X[s0.x * 32 + i];
        float xv1 = X[s1.x * 32 + i];
        float xv2 = X[s2.x * 32 + i];
        float xv3 = X[s3.x * 32 + i];
        EDGE_FMA(ea0, eb0, xv0);
        EDGE_FMA(ea1, eb1, xv1);
        EDGE_FMA(ea2, eb2, xv2);
        EDGE_FMA(ea3, eb3, xv3);
    }
    // tail (< 8 edges): halves interleave single edges
    for (int k = c + half; k < deg; k += 2) {
        int2 se = adj[base + k];
        float4 ea = *(const float4*)(E + (size_t)se.y * 8);
        float4 eb = *(const float4*)(E + (size_t)se.y * 8 + 4);
        float xv = X[se.x * 32 + i];
        EDGE_FMA(ea, eb, xv);
    }

    // merge halves
    g0 += __shfl_xor(g0, 32); g1 += __shfl_xor(g1, 32);
    g2 += __shfl_xor(g2, 32); g3 += __shfl_xor(g3, 32);
    g4 += __shfl_xor(g4, 32); g5 += __shfl_xor(g5, 32);
    g6 += __shfl_xor(g6, 32); g7 += __shfl_xor(g7, 32);
    g8 += __shfl_xor(g8, 32);

    if (half == 0) {
        float* gr = G + (size_t)n * 288;
        gr[0 * 32 + i] = g0; gr[1 * 32 + i] = g1;
        gr[2 * 32 + i] = g2; gr[3 * 32 + i] = g3;
        gr[4 * 32 + i] = g4; gr[5 * 32 + i] = g5;
        gr[6 * 32 + i] = g6; gr[7 * 32 + i] = g7;
        gr[256 + i] = g8;
    }
}

// Epilogue GEMM: out[n][o] = sum_k Gext[n][k] * W'[k][o], K=320, N=32.
//   W' = [knw | knb | root] verbatim; Gext rows 0..287 = G, rows 288..319 = X.
// Block: 64 nodes, 256 threads; thread (mg = t>>3, jg = t&7) -> nodes
// {2mg, 2mg+1} x outputs {4jg..4jg+3}. W' staged once in LDS (40KB); G/X
// streamed in 9 transposed k-chunks (<=36 x 64, stride 65).
// mode 0: H[n][o] = relu(out + bias[o]);  mode 1: util[n] = db + relu(.)@dw
__global__ __launch_bounds__(256) void epi_gemm(const float4* __restrict__ G4,
                                                const float4* __restrict__ X4,
                                                const float4* __restrict__ knw4,
                                                const float4* __restrict__ knb4,
                                                const float4* __restrict__ root4,
                                                const float* __restrict__ bias,
                                                const float* __restrict__ dw,
                                                const float* __restrict__ db,
                                                float* __restrict__ H,
                                                float* __restrict__ util,
                                                int mode) {
    __shared__ float Ws[320 * 32];   // 40960 B
    __shared__ float Gs[36 * 65];    //  9360 B
    int t = threadIdx.x;
    int nb = blockIdx.x * MB;

    // stage W' = [knw | knb | root] verbatim
    {
        float4* d = (float4*)Ws;
#pragma unroll
        for (int c = 0; c < 10; ++c) {
            int idx = c * 256 + t;
            float4 v;
            if (idx < 2048) v = knw4[idx];
            else if (idx < 2304) v = knb4[idx - 2048];
            else v = root4[idx - 2304];
            d[idx] = v;
        }
    }

    int mg = t >> 3, jg = t & 7;
    float4 a0 = make_float4(0.f, 0.f, 0.f, 0.f);
    float4 a1 = a0;
    int n0 = nb + 2 * mg, n1 = n0 + 1;

    for (int ch = 0; ch < 9; ++ch) {
        __syncthreads();  // Ws ready (ch 0) / previous chunk consumed
        if (ch < 8) {
            for (int idx = t; idx < MB * 9; idx += 256) {
                int n = idx / 9, k4 = idx % 9;
                float4 v = make_float4(0.f, 0.f, 0.f, 0.f);
                if (nb + n < N_NODES) v = G4[(size_t)(nb + n) * 72 + ch * 9 + k4];
                int r = k4 * 4;
                Gs[(r + 0) * 65 + n] = v.x; Gs[(r + 1) * 65 + n] = v.y;
                Gs[(r + 2) * 65 + n] = v.z; Gs[(r + 3) * 65 + n] = v.w;
            }
        } else {
            for (int idx = t; idx < MB * 8; idx += 256) {
                int n = idx / 8, k4 = idx % 8;
                float4 v = make_float4(0.f, 0.f, 0.f, 0.f);
                if (nb + n < N_NODES) v = X4[(size_t)(nb + n) * 8 + k4];
                int r = k4 * 4;
                Gs[(r + 0) * 65 + n] = v.x; Gs[(r + 1) * 65 + n] = v.y;
                Gs[(r + 2) * 65 + n] = v.z; Gs[(r + 3) * 65 + n] = v.w;
            }
        }
        __syncthreads();
        int kbase = (ch < 8) ? ch * 36 : 288;
        int klen = (ch < 8) ? 36 : 32;
        for (int kk = 0; kk < klen; ++kk) {
            float4 w = *(const float4*)&Ws[(kbase + kk) * 32 + jg * 4];
            float2 g = *(const float2*)&Gs[kk * 65 + 2 * mg];
            a0 = f4fma(g.x, w, a0);
            a1 = f4fma(g.y, w, a1);
        }
    }

    float4 b = ((const float4*)bias)[jg];
    if (mode == 0) {
        float4 v;
        if (n0 < N_NODES) {
            v.x = fmaxf(a0.x + b.x, 0.f); v.y = fmaxf(a0.y + b.y, 0.f);
            v.z = fmaxf(a0.z + b.z, 0.f); v.w = fmaxf(a0.w + b.w, 0.f);
            ((float4*)H)[n0 * 8 + jg] = v;
        }
        if (n1 < N_NODES) {
            v.x = fmaxf(a1.x + b.x, 0.f); v.y = fmaxf(a1.y + b.y, 0.f);
            v.z = fmaxf(a1.z + b.z, 0.f); v.w = fmaxf(a1.w + b.w, 0.f);
            ((float4*)H)[n1 * 8 + jg] = v;
        }
    } else {
        float4 dv = ((const float4*)dw)[jg];
        float p0 = fmaxf(a0.x + b.x, 0.f) * dv.x + fmaxf(a0.y + b.y, 0.f) * dv.y
                 + fmaxf(a0.z + b.z, 0.f) * dv.z + fmaxf(a0.w + b.w, 0.f) * dv.w;
        float p1 = fmaxf(a1.x + b.x, 0.f) * dv.x + fmaxf(a1.y + b.y, 0.f) * dv.y
                 + fmaxf(a1.z + b.z, 0.f) * dv.z + fmaxf(a1.w + b.w, 0.f) * dv.w;
        p0 += __shfl_xor(p0, 1); p1 += __shfl_xor(p1, 1);
        p0 += __shfl_xor(p0, 2); p1 += __shfl_xor(p1, 2);
        p0 += __shfl_xor(p0, 4); p1 += __shfl_xor(p1, 4);
        if (jg == 0) {
            float dbv = db[0];
            if (n0 < N_NODES) util[n0] = p0 + dbv;
            if (n1 < N_NODES) util[n1] = p1 + dbv;
        }
    }
}

// out[p] = util[idx_b[p]] - util[idx_a[p]]
__global__ void pair_kernel(const float* __restrict__ util, const int* __restrict__ ia,
                            const int* __restrict__ ib, float* __restrict__ out) {
    int p = blockIdx.x * blockDim.x + threadIdx.x;
    if (p >= N_PAIRS) return;
    out[p] = util[ib[p]] - util[ia[p]];
}

extern "C" void kernel_launch(void* const* d_in, const int* in_sizes, int n_in,
                              void* d_out, int out_size, void* d_ws, size_t ws_size,
                              hipStream_t stream) {
    const float* x     = (const float*)d_in[0];
    const float* e     = (const float*)d_in[1];
    const float* knw1  = (const float*)d_in[2];
    const float* knb1  = (const float*)d_in[3];
    const float* root1 = (const float*)d_in[4];
    const float* bias1 = (const float*)d_in[5];
    const float* knw2  = (const float*)d_in[6];
    const float* knb2  = (const float*)d_in[7];
    const float* root2 = (const float*)d_in[8];
    const float* bias2 = (const float*)d_in[9];
    const float* dw    = (const float*)d_in[10];
    const float* db    = (const float*)d_in[11];
    const int*   ei    = (const int*)d_in[12];
    const int*   ia    = (const int*)d_in[13];
    const int*   ib    = (const int*)d_in[14];
    float* out = (float*)d_out;

    float* ws = (float*)d_ws;
    float* G    = ws;                       // 20000*288 = 5,760,000 floats
    float* H    = ws + 5760000;             // 640,000
    float* util = ws + 6400000;             // 20,000
    int*   cnt  = (int*)(ws + 6420000);     // 20,000
    int2*  adj  = (int2*)(ws + 6440000);    // 960,000 int2 = 7.68 MB

    int nblk_epi = (N_NODES + MB - 1) / MB;          // 313
    int nblk_gat = (N_NODES * 64) / 256;             // 5000

    // ---- adjacency ----
    zero_cnt<<<(N_NODES + 255) / 256, 256, 0, stream>>>(cnt);
    fill_adj<<<(N_EDGES + 255) / 256, 256, 0, stream>>>(ei, cnt, adj);

    // ---- layer 1 ----
    edge_gather<<<nblk_gat, 256, 0, stream>>>(x, e, cnt, adj, G);
    epi_gemm<<<nblk_epi, 256, 0, stream>>>((const float4*)G, (const float4*)x,
                                           (const float4*)knw1, (const float4*)knb1,
                                           (const float4*)root1, bias1, dw, db,
                                           H, util, 0);
    // ---- layer 2 (+ readout) ----
    edge_gather<<<nblk_gat, 256, 0, stream>>>(H, e, cnt, adj, G);
    epi_gemm<<<nblk_epi, 256, 0, stream>>>((const float4*)G, (const float4*)H,
                                           (const float4*)knw2, (const float4*)knb2,
                                           (const float4*)root2, bias2, dw, db,
                                           H, util, 1);

    // ---- pairs ----
    pair_kernel<<<(N_PAIRS + 255) / 256, 256, 0, stream>>>(util, ia, ib, out);
}